// Round 13
// baseline (583.923 us; speedup 1.0000x reference)
//
#include <hip/hip_runtime.h>
#include <hip/hip_bf16.h>

// B=8, C=128, N=16384, NH=8, HD=16, D=128
#define N_SEQ 16384
#define EPSF 1e-6f

typedef unsigned short u16;
typedef unsigned int   u32;
typedef __attribute__((ext_vector_type(8)))  __bf16 bf16x8;
typedef __attribute__((ext_vector_type(4)))  float  f32x4;
typedef __attribute__((ext_vector_type(16))) float  f32x16;

union B8 { u32 w[4]; bf16x8 v; };

__device__ __forceinline__ int rfl(int x){ return __builtin_amdgcn_readfirstlane(x); }
__device__ __forceinline__ u16 f2b(float x){
  union { __hip_bfloat16 h; u16 u; } c; c.h = __float2bfloat16(x); return c.u;
}
__device__ __forceinline__ u32 pk2(float a, float b){
  return (u32)f2b(a) | ((u32)f2b(b) << 16);
}
__device__ __forceinline__ float bf2f(u16 v){ return __uint_as_float(((u32)v) << 16); }
#define MFMA(a,b,c)   __builtin_amdgcn_mfma_f32_16x16x32_bf16((a),(b),(c),0,0,0)
#define MFMA32(a,b,c) __builtin_amdgcn_mfma_f32_32x32x16_bf16((a),(b),(c),0,0,0)

// Swizzled LDS indexers (u16 units): linear rows, idx ^= (row&7)<<3.
__device__ __forceinline__ int xidx(int n, int f){ return n*128 + (f ^ ((n & 7) << 3)); } // [64 n][128 f]
__device__ __forceinline__ int kidx(int d, int n){ return d*64  + (n ^ ((d & 7) << 3)); } // [128 d][64 n]

#define QTS 16   // u16 stride of Qt rows (32B, 16B-aligned b128 reads)

// 16x16x32 GEMM (pass1): q[nt] += W @ X.
__device__ __forceinline__ void gemmW(const u16* __restrict__ Wb, int row, int ldw, int koff,
                                      const u16* __restrict__ Xl, int m, int g, f32x4 q[4]){
  #pragma unroll
  for (int ks = 0; ks < 4; ++ks){
    const bf16x8 av = *reinterpret_cast<const bf16x8*>(&Wb[(size_t)row*ldw + koff + ks*32 + g*8]);
    #pragma unroll
    for (int nt = 0; nt < 4; ++nt){
      const bf16x8 bv = *reinterpret_cast<const bf16x8*>(&Xl[xidx(nt*16+m, ks*32 + g*8)]);
      q[nt] = MFMA(av, bv, q[nt]);
    }
  }
}

// 32x32x16 GEMM (pass2): acc += W[rows rb32..+31] @ X^T over cols CB..CB+31.
// A: row=lm, k=ks*16+l5*8+j (global bf16 row-major). B: col=lm, same k (LDS [n][feat]).
// One b128 LDS read per MFMA -> half the LDS traffic of the 16x16 path.
__device__ __forceinline__ void gemm32(const u16* __restrict__ Wb, int rb32, int ldw, int koff,
                                       const u16* __restrict__ Xl, int CB, int lm, int l5,
                                       f32x16& acc){
  #pragma unroll
  for (int ks = 0; ks < 8; ++ks){
    const bf16x8 av = *reinterpret_cast<const bf16x8*>(
        &Wb[(size_t)(rb32 + lm)*ldw + koff + ks*16 + l5*8]);
    const bf16x8 bv = *reinterpret_cast<const bf16x8*>(
        &Xl[xidx(CB + lm, ks*16 + l5*8)]);
    acc = MFMA32(av, bv, acc);
  }
}

// One attention+Wback stage. Wave owns rows rb32..rb32+31 (heads 2W,2W+1), cols CB..CB+31.
// 32x32 C/D mapping: row=(reg&3)+8*(reg>>2)+4*l5, col=lm. T master in Xl (bf16, owner RMW).
template<int NSRC>
__device__ __forceinline__ void stage32(u16* Xl, u16* Ul, u16* Qt,
    const u16* __restrict__ wqb, const u16* __restrict__ wbb,
    const u32* __restrict__ kvb, const float* __restrict__ ksf,
    int s1, int s2, int b, int W, int CB, int lm, int l5, int g, int m, int rb32){
  // q = relu(Wq @ T) + eps
  f32x16 q;
  #pragma unroll
  for (int r = 0; r < 16; ++r) q[r] = 0.f;
  gemm32(wqb, rb32, 128, 0, Xl, CB, lm, l5, q);
  #pragma unroll
  for (int r = 0; r < 16; ++r) q[r] = fmaxf(q[r], 0.f) + EPSF;
  // attention per head: j=0 -> head 2W (regs 0-7), j=1 -> head 2W+1 (regs 8-15)
  #pragma unroll
  for (int j = 0; j < 2; ++j){
    const int h  = 2*W + j;
    const int qb = 8*j;
    const int sA = ((s1*8 + b)*8 + h);
    const int sB = ((s2*8 + b)*8 + h);
    // z-dot: lane's 8 d-values are d = {4*l5+0..3, 8+4*l5+0..3}
    float4 a0 = *reinterpret_cast<const float4*>(ksf + sA*16 + 4*l5);
    float4 a1 = *reinterpret_cast<const float4*>(ksf + sA*16 + 8 + 4*l5);
    float p1 = q[qb+0]*a0.x + q[qb+1]*a0.y + q[qb+2]*a0.z + q[qb+3]*a0.w
             + q[qb+4]*a1.x + q[qb+5]*a1.y + q[qb+6]*a1.z + q[qb+7]*a1.w;
    p1 += __shfl_xor(p1, 32);
    float z1 = 1.0f / (p1 + EPSF);
    float z2 = 0.f;
    if (NSRC == 2){
      float4 b0 = *reinterpret_cast<const float4*>(ksf + sB*16 + 4*l5);
      float4 b1 = *reinterpret_cast<const float4*>(ksf + sB*16 + 8 + 4*l5);
      float p2 = q[qb+0]*b0.x + q[qb+1]*b0.y + q[qb+2]*b0.z + q[qb+3]*b0.w
               + q[qb+4]*b1.x + q[qb+5]*b1.y + q[qb+6]*b1.z + q[qb+7]*b1.w;
      p2 += __shfl_xor(p2, 32);
      z2 = 1.0f / (p2 + EPSF);
    }
    // qh^T into Qt[h][n=CB+lm][d]: regs qb+0..3 -> d=4*l5.., regs qb+4..7 -> d=8+4*l5..
    u16* qrow = Qt + h*(64*QTS) + (CB + lm)*QTS;
    *reinterpret_cast<uint2*>(&qrow[4*l5]) =
      make_uint2(pk2(q[qb+0], q[qb+1]), pk2(q[qb+2], q[qb+3]));
    *reinterpret_cast<uint2*>(&qrow[8 + 4*l5]) =
      make_uint2(pk2(q[qb+4], q[qb+5]), pk2(q[qb+6], q[qb+7]));
    // PV (16x16): A = prepacked KV frags; B from Qt; z redistributed by shfl to PV cols
    B8 kA, kB;
    uint4 ka4 = *reinterpret_cast<const uint4*>(&kvb[sA*128 + (g&1)*64 + m*4]);
    kA.w[0]=ka4.x; kA.w[1]=ka4.y; kA.w[2]=ka4.z; kA.w[3]=ka4.w;
    if (NSRC == 2){
      uint4 kb4 = *reinterpret_cast<const uint4*>(&kvb[sB*128 + (g&1)*64 + m*4]);
      kB.w[0]=kb4.x; kB.w[1]=kb4.y; kB.w[2]=kb4.z; kB.w[3]=kb4.w;
    }
    #pragma unroll
    for (int nt = 0; nt < 2; ++nt){
      float zp1 = __shfl(z1, nt*16 + m);
      float zp2 = (NSRC == 2) ? __shfl(z2, nt*16 + m) : 0.f;
      B8 bb;
      if (g < 2) bb.v = *reinterpret_cast<const bf16x8*>(
          &Qt[h*(64*QTS) + (CB + nt*16 + m)*QTS + g*8]);
      else { bb.w[0]=0u; bb.w[1]=0u; bb.w[2]=0u; bb.w[3]=0u; }
      const f32x4 z4 = (f32x4){0.f,0.f,0.f,0.f};
      f32x4 Uv = MFMA(kA.v, bb.v, z4) * zp1;
      if (NSRC == 2) Uv += MFMA(kB.v, bb.v, z4) * zp2;
      *reinterpret_cast<uint2*>(&Ul[xidx(CB + nt*16 + m, h*16 + 4*g)]) =
        make_uint2(pk2(Uv[0], Uv[1]), pk2(Uv[2], Uv[3]));
    }
  }
  // preload old T into Wback accumulator (C-in add); rows rb32+8*rg+4*l5+0..3 at col CB+lm
  f32x16 t4;
  #pragma unroll
  for (int rg = 0; rg < 4; ++rg){
    uint2 o = *reinterpret_cast<const uint2*>(&Xl[xidx(CB + lm, rb32 + 8*rg + 4*l5)]);
    t4[4*rg+0] = bf2f((u16)(o.x & 0xffffu));
    t4[4*rg+1] = bf2f((u16)(o.x >> 16));
    t4[4*rg+2] = bf2f((u16)(o.y & 0xffffu));
    t4[4*rg+3] = bf2f((u16)(o.y >> 16));
  }
  __syncthreads();
  // T += Wback @ U
  gemm32(wbb, rb32, 128, 0, Ul, CB, lm, l5, t4);
  #pragma unroll
  for (int rg = 0; rg < 4; ++rg)
    *reinterpret_cast<uint2*>(&Xl[xidx(CB + lm, rb32 + 8*rg + 4*l5)]) =
      make_uint2(pk2(t4[4*rg+0], t4[4*rg+1]), pk2(t4[4*rg+2], t4[4*rg+3]));
  __syncthreads();
}

// ---------------- Prepack: all weights -> bf16 row-major (MFMA-ready) ------------------------------
__global__ void k_prepack(const float* __restrict__ Wq, const float* __restrict__ Wk,
                          const float* __restrict__ Wv, const float* __restrict__ Wb,
                          const float* __restrict__ Wo,
                          u16* __restrict__ wqb, u16* __restrict__ wkb, u16* __restrict__ wvb,
                          u16* __restrict__ wbb, u16* __restrict__ wob){
  int i = blockIdx.x*256 + threadIdx.x;     // grid 448*256 = 114688
  if      (i < 16384) wqb[i]         = f2b(Wq[i]);
  else if (i < 32768) wkb[i - 16384] = f2b(Wk[i - 16384]);
  else if (i < 49152) wvb[i - 32768] = f2b(Wv[i - 32768]);
  else if (i < 65536) wbb[i - 49152] = f2b(Wb[i - 49152]);
  else                wob[i - 65536] = f2b(Wo[i - 65536]);
}

// ---------------- Pass 1: partial KV/Ks per 1024-n chunk (MFMA; HBM-bound) -------------------------
__global__ __launch_bounds__(512, 4) void k_pass1(const float* __restrict__ t1,
    const float* __restrict__ t2, const float* __restrict__ t3, const float* __restrict__ fs,
    const u16* __restrict__ wkb, const u16* __restrict__ wvb,
    float* __restrict__ pkv, float* __restrict__ pks){
  __shared__ u16 Xl [64*128];    // 16384 B
  __shared__ u16 khl[128*64];    // 16384 B
  __shared__ u16 vl [128*64];    // 16384 B  -> 49152 B
  int bid = blockIdx.x;
  int ch = bid & 15, b = (bid >> 4) & 7, s = bid >> 7;
  int tid = threadIdx.x, lane = tid & 63;
  int w = rfl(tid >> 6), rb = w*16;
  int g = lane >> 4, m = lane & 15;
  const float* src = (s==0)?t1:(s==1)?t2:(s==2)?t3:fs;
  src += (size_t)b*128*N_SEQ + ch*1024;
  f32x4 kvacc = (f32x4){0.f,0.f,0.f,0.f};
  float ksump[4] = {0.f,0.f,0.f,0.f};
  #pragma unroll 1
  for (int tile = 0; tile < 16; ++tile){
    const float* sp = src + tile*64;
    #pragma unroll
    for (int rr = 0; rr < 8; ++rr){        // coalesced along n; packed u32 LDS writes
      int c = w*16 + rr*2;
      float f0 = sp[(size_t)c*N_SEQ + lane];
      float f1 = sp[(size_t)(c+1)*N_SEQ + lane];
      *reinterpret_cast<u32*>(&Xl[xidx(lane, c)]) = pk2(f0, f1);
    }
    __syncthreads();
    f32x4 kh[4], vv[4];
    #pragma unroll
    for (int nt = 0; nt < 4; ++nt){ kh[nt] = (f32x4){0.f,0.f,0.f,0.f}; vv[nt] = kh[nt]; }
    gemmW(wkb, rb + m, 128, 0, Xl, m, g, kh);
    gemmW(wvb, rb + m, 128, 0, Xl, m, g, vv);
    #pragma unroll
    for (int nt = 0; nt < 4; ++nt)
      #pragma unroll
      for (int r = 0; r < 4; ++r){
        float x = fmaxf(kh[nt][r], 0.f) + EPSF;   // kh = relu(.)+eps
        ksump[r] += x;
        khl[kidx(rb + 4*g + r, nt*16 + m)] = f2b(x);
        vl [kidx(rb + 4*g + r, nt*16 + m)] = f2b(vv[nt][r]);
      }
    __syncthreads();
    // KV_w += kh_w(16 x 64n) @ v_w^T : A[d][k=n], B[k=n][col=m-feat]
    #pragma unroll
    for (int ks2 = 0; ks2 < 2; ++ks2){
      const bf16x8 av = *reinterpret_cast<const bf16x8*>(&khl[kidx(rb+m, ks2*32 + g*8)]);
      const bf16x8 bv = *reinterpret_cast<const bf16x8*>(&vl [kidx(rb+m, ks2*32 + g*8)]);
      kvacc = MFMA(av, bv, kvacc);
    }
  }
  size_t pb = (((size_t)(ch*4 + s)*8 + b)*8 + w)*256;
  #pragma unroll
  for (int r = 0; r < 4; ++r)
    pkv[pb + (size_t)(4*g + r)*16 + m] = kvacc[r];
  #pragma unroll
  for (int r = 0; r < 4; ++r){
    float v2 = ksump[r];
    v2 += __shfl_xor(v2, 1); v2 += __shfl_xor(v2, 2);
    v2 += __shfl_xor(v2, 4); v2 += __shfl_xor(v2, 8);
    if (m == 0) pks[(((size_t)(ch*4 + s)*8 + b)*8 + w)*16 + 4*g + r] = v2;
  }
}

// ---------------- Reduce partials; emit KV as prepacked bf16 A-fragments ---------------------------
__global__ void k_reduce(const float* __restrict__ pkv, const float* __restrict__ pks,
                         u32* __restrict__ kvb, float* __restrict__ ksf){
  int i = blockIdx.x*256 + threadIdx.x;   // grid 144*256 = 36864
  if (i < 32768){
    int sA = i >> 7, r7 = i & 127;
    int gb = r7 >> 6, m = (r7 >> 2) & 15, t = r7 & 3;
    int d = gb*8 + 2*t;
    float a0 = 0.f, a1 = 0.f;
    #pragma unroll
    for (int ch = 0; ch < 16; ++ch){
      a0 += pkv[(size_t)ch*65536 + sA*256 + d*16 + m];
      a1 += pkv[(size_t)ch*65536 + sA*256 + (d+1)*16 + m];
    }
    kvb[i] = pk2(a0, a1);
  } else {
    int j = i - 32768;   // < 4096
    float a = 0.f;
    #pragma unroll
    for (int ch = 0; ch < 16; ++ch) a += pks[(size_t)ch*4096 + j];
    ksf[j] = a;
  }
}

// ---------------- Pass 2: fused pipeline; heavy GEMMs on 32x32x16 (half the LDS traffic) -----------
__global__ __launch_bounds__(512, 4) void k_pass2(const float* __restrict__ t1,
    const float* __restrict__ t2, const float* __restrict__ t3, const float* __restrict__ fs,
    const u16* __restrict__ wqb, const u16* __restrict__ wbb, const u16* __restrict__ wob,
    const u32* __restrict__ kvb, const float* __restrict__ ksf, float* __restrict__ outp){
  __shared__ u16 Xl[64*128];       // 16384 B
  __shared__ u16 Ul[64*128];       // 16384 B
  __shared__ u16 Qt[8*64*QTS];     // 16384 B -> 49152 B
  int bid = blockIdx.x;
  int b = bid >> 8, n0 = (bid & 255) * 64;
  int tid = threadIdx.x, lane = tid & 63;
  int w = rfl(tid >> 6);
  int W = w >> 1, CB = (w & 1) * 32, rb32 = W * 32;   // wave: rows rb32..+31, cols CB..+31
  int lm = lane & 31, l5 = lane >> 5;
  int g = lane >> 4, m = lane & 15;
  f32x16 oacc;
  #pragma unroll
  for (int r = 0; r < 16; ++r) oacc[r] = 0.f;

  #pragma unroll 1
  for (int i = 0; i < 3; ++i){
    const float* src = (i==0)?t1:(i==1)?t2:t3;
    int s1 = (i==0)?1:0, s2 = (i==2)?1:2;
    // ---- write t_i tile to Xl (bf16), 32x32-C/D-compatible ownership ----
    #pragma unroll
    for (int rg = 0; rg < 4; ++rg){
      int f = rb32 + 8*rg + 4*l5;
      float v0 = src[(size_t)(b*128 + f + 0)*N_SEQ + n0 + CB + lm];
      float v1 = src[(size_t)(b*128 + f + 1)*N_SEQ + n0 + CB + lm];
      float v2 = src[(size_t)(b*128 + f + 2)*N_SEQ + n0 + CB + lm];
      float v3 = src[(size_t)(b*128 + f + 3)*N_SEQ + n0 + CB + lm];
      *reinterpret_cast<uint2*>(&Xl[xidx(CB + lm, f)]) =
        make_uint2(pk2(v0, v1), pk2(v2, v3));
    }
    __syncthreads();
    stage32<2>(Xl, Ul, Qt, wqb, wbb, kvb, ksf, s1, s2, b, W, CB, lm, l5, g, m, rb32); // stage A
    stage32<1>(Xl, Ul, Qt, wqb, wbb, kvb, ksf, 3, 3, b, W, CB, lm, l5, g, m, rb32);   // stage B
    // acc += Wout[:, i*128 : i*128+128] @ t_if
    gemm32(wob, rb32, 384, i*128, Xl, CB, lm, l5, oacc);
    __syncthreads();   // before next i overwrites Xl
  }
  #pragma unroll
  for (int rg = 0; rg < 4; ++rg)
    #pragma unroll
    for (int rr = 0; rr < 4; ++rr){
      int f = rb32 + 8*rg + 4*l5 + rr;
      size_t idx = (size_t)(b*128 + f)*N_SEQ + n0 + CB + lm;
      outp[idx] = oacc[4*rg + rr] + fs[idx];
    }
}

extern "C" void kernel_launch(void* const* d_in, const int* in_sizes, int n_in,
                              void* d_out, int out_size, void* d_ws, size_t ws_size,
                              hipStream_t stream){
  const float* t1 = (const float*)d_in[0];
  const float* t2 = (const float*)d_in[1];
  const float* t3 = (const float*)d_in[2];
  const float* fs = (const float*)d_in[3];
  const float* Wq = (const float*)d_in[4];
  const float* Wk = (const float*)d_in[5];
  const float* Wv = (const float*)d_in[6];
  const float* Wb = (const float*)d_in[7];
  const float* Wo = (const float*)d_in[8];
  float* outp = (float*)d_out;
  float* ws = (float*)d_ws;
  // ws layout (float units):
  //   pkv [16*65536] | pks [16*4096] | ksf [4096] | kvb [32768 u32]
  //   | wqb,wkb,wvb,wbb [4 * 8192] | wob [24576]     (bf16 halves in float-sized slots)
  float* pkv = ws;
  float* pks = ws + 16*65536;
  float* ksf = ws + 16*65536 + 16*4096;
  u32*  kvb  = (u32*)(ksf + 4096);
  u16*  wqb  = (u16*)(kvb + 32768);
  u16*  wkb  = wqb + 16384;
  u16*  wvb  = wkb + 16384;
  u16*  wbb  = wvb + 16384;
  u16*  wob  = wbb + 16384;   // 49152 u16

  k_prepack<<<dim3(448),  dim3(256), 0, stream>>>(Wq, Wk, Wv, Wb, Wo, wqb, wkb, wvb, wbb, wob);
  k_pass1  <<<dim3(512),  dim3(512), 0, stream>>>(t1, t2, t3, fs, wkb, wvb, pkv, pks);
  k_reduce <<<dim3(144),  dim3(256), 0, stream>>>(pkv, pks, kvb, ksf);
  k_pass2  <<<dim3(2048), dim3(512), 0, stream>>>(t1, t2, t3, fs, wqb, wbb, wob, kvb, ksf, outp);
}

// Round 14
// 205.403 us; speedup vs baseline: 2.8428x; 2.8428x over previous
//
#include <hip/hip_runtime.h>
#include <hip/hip_bf16.h>

// B=8, C=128, N=16384, NH=8, HD=16, D=128
#define N_SEQ 16384
#define EPSF 1e-6f

typedef unsigned short u16;
typedef unsigned int   u32;
typedef __attribute__((ext_vector_type(8))) __bf16 bf16x8;
typedef __attribute__((ext_vector_type(4))) float  f32x4;

union B8 { u32 w[4]; bf16x8 v; };

__device__ __forceinline__ int rfl(int x){ return __builtin_amdgcn_readfirstlane(x); }
__device__ __forceinline__ u16 f2b(float x){
  union { __hip_bfloat16 h; u16 u; } c; c.h = __float2bfloat16(x); return c.u;
}
__device__ __forceinline__ u32 pk2(float a, float b){
  return (u32)f2b(a) | ((u32)f2b(b) << 16);
}
__device__ __forceinline__ float bf2f(u16 v){ return __uint_as_float(((u32)v) << 16); }
#define MFMA(a,b,c) __builtin_amdgcn_mfma_f32_16x16x32_bf16((a),(b),(c),0,0,0)

// Swizzled LDS indexers (u16 units): linear rows, idx ^= (row&7)<<3.
__device__ __forceinline__ int xidx(int n, int f){ return n*128 + (f ^ ((n & 7) << 3)); } // [64 n][128 f]
__device__ __forceinline__ int kidx(int d, int n){ return d*64  + (n ^ ((d & 7) << 3)); } // [128 d][64 n]

#define QTS 24   // u16 stride of Qt rows (48B: 16B-aligned for ds_read_b128)

// q[nt] += W @ X.  W: prepacked bf16 row-major (ldw u16/row) — A-frags load directly, no cvt.
__device__ __forceinline__ void gemmW(const u16* __restrict__ Wb, int row, int ldw, int koff,
                                      const u16* __restrict__ Xl, int m, int g, f32x4 q[4]){
  #pragma unroll
  for (int ks = 0; ks < 4; ++ks){
    const bf16x8 av = *reinterpret_cast<const bf16x8*>(&Wb[(size_t)row*ldw + koff + ks*32 + g*8]);
    #pragma unroll
    for (int nt = 0; nt < 4; ++nt){
      const bf16x8 bv = *reinterpret_cast<const bf16x8*>(&Xl[xidx(nt*16+m, ks*32 + g*8)]);
      q[nt] = MFMA(av, bv, q[nt]);
    }
  }
}

// One attention+Wback stage: T += Wback @ [ sum_s z_s * (qh @ KV_s) ],  qh = relu(Wq@T)+eps.
// T's master copy lives as bf16 in Xl (each element owned by one thread -> safe RMW).
// PV B-fragments come from a per-head LDS transpose buffer Qt (within-wave prod/cons, no barrier).
template<int NSRC>
__device__ __forceinline__ void stage(u16* Xl, u16* Ul, u16* Qt,
    const u16* __restrict__ wqb, const u16* __restrict__ wbb,
    const u32* __restrict__ kvb, const float* __restrict__ ksf,
    int s1, int s2, int b, int w, int g, int m, int rb){
  const int sA = ((s1*8 + b)*8 + w);
  const int sB = ((s2*8 + b)*8 + w);
  float4 ksA = *reinterpret_cast<const float4*>(ksf + sA*16 + 4*g);
  float4 ksB = ksA;
  // KV A-fragment: prepacked pairs, one dwordx4 per source
  B8 kA, kB;
  uint4 ka4 = *reinterpret_cast<const uint4*>(&kvb[sA*128 + (g&1)*64 + m*4]);
  kA.w[0]=ka4.x; kA.w[1]=ka4.y; kA.w[2]=ka4.z; kA.w[3]=ka4.w;
  if (NSRC == 2){
    ksB = *reinterpret_cast<const float4*>(ksf + sB*16 + 4*g);
    uint4 kb4 = *reinterpret_cast<const uint4*>(&kvb[sB*128 + (g&1)*64 + m*4]);
    kB.w[0]=kb4.x; kB.w[1]=kb4.y; kB.w[2]=kb4.z; kB.w[3]=kb4.w;
  }
  // qh = relu(Wq @ X) + eps  (C/D regs: row rb+4g+r, col nt*16+m)
  f32x4 q[4];
  #pragma unroll
  for (int nt = 0; nt < 4; ++nt) q[nt] = (f32x4){0.f,0.f,0.f,0.f};
  gemmW(wqb, rb + m, 128, 0, Xl, m, g, q);
  #pragma unroll
  for (int nt = 0; nt < 4; ++nt)
    #pragma unroll
    for (int r = 0; r < 4; ++r) q[nt][r] = fmaxf(q[nt][r], 0.f) + EPSF;
  // z_s(n, h=w) = 1/(qh . Ks_s + eps): partial over own 4 rows, reduce over lane-groups
  float z1[4], z2[4];
  #pragma unroll
  for (int nt = 0; nt < 4; ++nt){
    float p = q[nt][0]*ksA.x + q[nt][1]*ksA.y + q[nt][2]*ksA.z + q[nt][3]*ksA.w;
    p += __shfl_xor(p, 16); p += __shfl_xor(p, 32);
    z1[nt] = 1.0f / (p + EPSF);
  }
  if (NSRC == 2){
    #pragma unroll
    for (int nt = 0; nt < 4; ++nt){
      float p = q[nt][0]*ksB.x + q[nt][1]*ksB.y + q[nt][2]*ksB.z + q[nt][3]*ksB.w;
      p += __shfl_xor(p, 16); p += __shfl_xor(p, 32);
      z2[nt] = 1.0f / (p + EPSF);
    }
  }
  // qh^T into Qt[head][n][d] (bf16, stride QTS): lane owns d=4g..4g+3 at col n=nt*16+m
  u16* qrow = Qt + w*(64*QTS);
  #pragma unroll
  for (int nt = 0; nt < 4; ++nt)
    *reinterpret_cast<uint2*>(&qrow[(nt*16+m)*QTS + 4*g]) =
      make_uint2(pk2(q[nt][0], q[nt][1]), pk2(q[nt][2], q[nt][3]));
  // PV: B[k=d][col] = Qt[n=nt*16+col][d=g*8+j] (g<2; k>=16 zero-padded)
  #pragma unroll
  for (int nt = 0; nt < 4; ++nt){
    B8 bb;
    if (g < 2) bb.v = *reinterpret_cast<const bf16x8*>(&qrow[(nt*16+m)*QTS + g*8]);
    else { bb.w[0]=0u; bb.w[1]=0u; bb.w[2]=0u; bb.w[3]=0u; }
    const f32x4 z4 = (f32x4){0.f,0.f,0.f,0.f};
    f32x4 S1 = MFMA(kA.v, bb.v, z4);
    f32x4 Uv = S1 * z1[nt];
    if (NSRC == 2){
      f32x4 S2 = MFMA(kB.v, bb.v, z4);
      Uv += S2 * z2[nt];
    }
    *reinterpret_cast<uint2*>(&Ul[xidx(nt*16+m, rb + 4*g)]) =
      make_uint2(pk2(Uv[0], Uv[1]), pk2(Uv[2], Uv[3]));
  }
  // preload old T into the Wback accumulator (MFMA C-in does the add); Xl stable until we store
  f32x4 t4[4];
  #pragma unroll
  for (int nt = 0; nt < 4; ++nt){
    uint2 old = *reinterpret_cast<const uint2*>(&Xl[xidx(nt*16+m, rb + 4*g)]);
    t4[nt][0] = bf2f((u16)(old.x & 0xffffu));
    t4[nt][1] = bf2f((u16)(old.x >> 16));
    t4[nt][2] = bf2f((u16)(old.y & 0xffffu));
    t4[nt][3] = bf2f((u16)(old.y >> 16));
  }
  __syncthreads();
  // T += Wback @ U
  gemmW(wbb, rb + m, 128, 0, Ul, m, g, t4);
  #pragma unroll
  for (int nt = 0; nt < 4; ++nt)
    *reinterpret_cast<uint2*>(&Xl[xidx(nt*16+m, rb + 4*g)]) =
      make_uint2(pk2(t4[nt][0], t4[nt][1]), pk2(t4[nt][2], t4[nt][3]));
  __syncthreads();
}

// ---------------- Prepack: all weights -> bf16 row-major (MFMA-ready) ------------------------------
__global__ void k_prepack(const float* __restrict__ Wq, const float* __restrict__ Wk,
                          const float* __restrict__ Wv, const float* __restrict__ Wb,
                          const float* __restrict__ Wo,
                          u16* __restrict__ wqb, u16* __restrict__ wkb, u16* __restrict__ wvb,
                          u16* __restrict__ wbb, u16* __restrict__ wob){
  int i = blockIdx.x*256 + threadIdx.x;     // grid 448*256 = 114688
  if      (i < 16384) wqb[i]         = f2b(Wq[i]);
  else if (i < 32768) wkb[i - 16384] = f2b(Wk[i - 16384]);
  else if (i < 49152) wvb[i - 32768] = f2b(Wv[i - 32768]);
  else if (i < 65536) wbb[i - 49152] = f2b(Wb[i - 49152]);
  else                wob[i - 65536] = f2b(Wo[i - 65536]);
}

// ---------------- Pass 1: partial KV/Ks per 1024-n chunk (MFMA; HBM-bound) -------------------------
__global__ __launch_bounds__(512, 4) void k_pass1(const float* __restrict__ t1,
    const float* __restrict__ t2, const float* __restrict__ t3, const float* __restrict__ fs,
    const u16* __restrict__ wkb, const u16* __restrict__ wvb,
    float* __restrict__ pkv, float* __restrict__ pks){
  __shared__ u16 Xl [64*128];    // 16384 B
  __shared__ u16 khl[128*64];    // 16384 B
  __shared__ u16 vl [128*64];    // 16384 B  -> 49152 B
  int bid = blockIdx.x;
  int ch = bid & 15, b = (bid >> 4) & 7, s = bid >> 7;
  int tid = threadIdx.x, lane = tid & 63;
  int w = rfl(tid >> 6), rb = w*16;
  int g = lane >> 4, m = lane & 15;
  const float* src = (s==0)?t1:(s==1)?t2:(s==2)?t3:fs;
  src += (size_t)b*128*N_SEQ + ch*1024;
  f32x4 kvacc = (f32x4){0.f,0.f,0.f,0.f};
  float ksump[4] = {0.f,0.f,0.f,0.f};
  #pragma unroll 1
  for (int tile = 0; tile < 16; ++tile){
    const float* sp = src + tile*64;
    #pragma unroll
    for (int rr = 0; rr < 8; ++rr){        // coalesced along n; packed u32 LDS writes
      int c = w*16 + rr*2;
      float f0 = sp[(size_t)c*N_SEQ + lane];
      float f1 = sp[(size_t)(c+1)*N_SEQ + lane];
      *reinterpret_cast<u32*>(&Xl[xidx(lane, c)]) = pk2(f0, f1);
    }
    __syncthreads();
    f32x4 kh[4], vv[4];
    #pragma unroll
    for (int nt = 0; nt < 4; ++nt){ kh[nt] = (f32x4){0.f,0.f,0.f,0.f}; vv[nt] = kh[nt]; }
    gemmW(wkb, rb + m, 128, 0, Xl, m, g, kh);
    gemmW(wvb, rb + m, 128, 0, Xl, m, g, vv);
    #pragma unroll
    for (int nt = 0; nt < 4; ++nt)
      #pragma unroll
      for (int r = 0; r < 4; ++r){
        float x = fmaxf(kh[nt][r], 0.f) + EPSF;   // kh = relu(.)+eps
        ksump[r] += x;
        khl[kidx(rb + 4*g + r, nt*16 + m)] = f2b(x);
        vl [kidx(rb + 4*g + r, nt*16 + m)] = f2b(vv[nt][r]);
      }
    __syncthreads();
    // KV_w += kh_w(16 x 64n) @ v_w^T : A[d][k=n], B[k=n][col=m-feat]
    #pragma unroll
    for (int ks2 = 0; ks2 < 2; ++ks2){
      const bf16x8 av = *reinterpret_cast<const bf16x8*>(&khl[kidx(rb+m, ks2*32 + g*8)]);
      const bf16x8 bv = *reinterpret_cast<const bf16x8*>(&vl [kidx(rb+m, ks2*32 + g*8)]);
      kvacc = MFMA(av, bv, kvacc);
    }
  }
  size_t pb = (((size_t)(ch*4 + s)*8 + b)*8 + w)*256;
  #pragma unroll
  for (int r = 0; r < 4; ++r)
    pkv[pb + (size_t)(4*g + r)*16 + m] = kvacc[r];
  #pragma unroll
  for (int r = 0; r < 4; ++r){
    float v2 = ksump[r];
    v2 += __shfl_xor(v2, 1); v2 += __shfl_xor(v2, 2);
    v2 += __shfl_xor(v2, 4); v2 += __shfl_xor(v2, 8);
    if (m == 0) pks[(((size_t)(ch*4 + s)*8 + b)*8 + w)*16 + 4*g + r] = v2;
  }
}

// ---------------- Reduce partials; emit KV as prepacked bf16 A-fragments ---------------------------
__global__ void k_reduce(const float* __restrict__ pkv, const float* __restrict__ pks,
                         u32* __restrict__ kvb, float* __restrict__ ksf){
  int i = blockIdx.x*256 + threadIdx.x;   // grid 144*256 = 36864
  if (i < 32768){
    int sA = i >> 7, r7 = i & 127;
    int gb = r7 >> 6, m = (r7 >> 2) & 15, t = r7 & 3;
    int d = gb*8 + 2*t;
    float a0 = 0.f, a1 = 0.f;
    #pragma unroll
    for (int ch = 0; ch < 16; ++ch){
      a0 += pkv[(size_t)ch*65536 + sA*256 + d*16 + m];
      a1 += pkv[(size_t)ch*65536 + sA*256 + (d+1)*16 + m];
    }
    kvb[i] = pk2(a0, a1);
  } else {
    int j = i - 32768;   // < 4096
    float a = 0.f;
    #pragma unroll
    for (int ch = 0; ch < 16; ++ch) a += pks[(size_t)ch*4096 + j];
    ksf[j] = a;
  }
}

// ---------------- Pass 2: fused per-n pipeline, all GEMMs on MFMA ----------------------------------
__global__ __launch_bounds__(512, 4) void k_pass2(const float* __restrict__ t1,
    const float* __restrict__ t2, const float* __restrict__ t3, const float* __restrict__ fs,
    const u16* __restrict__ wqb, const u16* __restrict__ wbb, const u16* __restrict__ wob,
    const u32* __restrict__ kvb, const float* __restrict__ ksf, float* __restrict__ outp){
  __shared__ u16 Xl[64*128];       // 16384 B
  __shared__ u16 Ul[64*128];       // 16384 B
  __shared__ u16 Qt[8*64*QTS];     // 24576 B -> total 57344 B
  int bid = blockIdx.x;
  int b = bid >> 8, n0 = (bid & 255) * 64;
  int tid = threadIdx.x, lane = tid & 63;
  int w = rfl(tid >> 6), rb = w*16;
  int g = lane >> 4, m = lane & 15;
  f32x4 oacc[4];
  #pragma unroll
  for (int nt = 0; nt < 4; ++nt) oacc[nt] = (f32x4){0.f,0.f,0.f,0.f};

  #pragma unroll 1
  for (int i = 0; i < 3; ++i){
    const float* src = (i==0)?t1:(i==1)?t2:t3;
    int s1 = (i==0)?1:0, s2 = (i==2)?1:2;
    #pragma unroll
    for (int nt = 0; nt < 4; ++nt){
      float f0 = src[(size_t)(b*128 + rb + 4*g + 0)*N_SEQ + n0 + nt*16 + m];
      float f1 = src[(size_t)(b*128 + rb + 4*g + 1)*N_SEQ + n0 + nt*16 + m];
      float f2 = src[(size_t)(b*128 + rb + 4*g + 2)*N_SEQ + n0 + nt*16 + m];
      float f3 = src[(size_t)(b*128 + rb + 4*g + 3)*N_SEQ + n0 + nt*16 + m];
      *reinterpret_cast<uint2*>(&Xl[xidx(nt*16+m, rb + 4*g)]) =
        make_uint2(pk2(f0, f1), pk2(f2, f3));
    }
    __syncthreads();
    stage<2>(Xl, Ul, Qt, wqb, wbb, kvb, ksf, s1, s2, b, w, g, m, rb);  // stage A
    stage<1>(Xl, Ul, Qt, wqb, wbb, kvb, ksf, 3, 3, b, w, g, m, rb);    // stage B
    // acc += Wout[:, i*128 : i*128+128] @ t_if
    gemmW(wob, rb + m, 384, i*128, Xl, m, g, oacc);
    __syncthreads();   // before next i overwrites Xl
  }
  #pragma unroll
  for (int nt = 0; nt < 4; ++nt)
    #pragma unroll
    for (int r = 0; r < 4; ++r){
      size_t idx = (size_t)(b*128 + rb + 4*g + r)*N_SEQ + n0 + nt*16 + m;
      outp[idx] = oacc[nt][r] + fs[idx];
    }
}

extern "C" void kernel_launch(void* const* d_in, const int* in_sizes, int n_in,
                              void* d_out, int out_size, void* d_ws, size_t ws_size,
                              hipStream_t stream){
  const float* t1 = (const float*)d_in[0];
  const float* t2 = (const float*)d_in[1];
  const float* t3 = (const float*)d_in[2];
  const float* fs = (const float*)d_in[3];
  const float* Wq = (const float*)d_in[4];
  const float* Wk = (const float*)d_in[5];
  const float* Wv = (const float*)d_in[6];
  const float* Wb = (const float*)d_in[7];
  const float* Wo = (const float*)d_in[8];
  float* outp = (float*)d_out;
  float* ws = (float*)d_ws;
  // ws layout (float units):
  //   pkv [16*65536] | pks [16*4096] | ksf [4096] | kvb [32768 u32]
  //   | wqb,wkb,wvb,wbb [4 * 8192] | wob [24576]     (bf16 halves in float-sized slots)
  float* pkv = ws;
  float* pks = ws + 16*65536;
  float* ksf = ws + 16*65536 + 16*4096;
  u32*  kvb  = (u32*)(ksf + 4096);
  u16*  wqb  = (u16*)(kvb + 32768);
  u16*  wkb  = wqb + 16384;
  u16*  wvb  = wkb + 16384;
  u16*  wbb  = wvb + 16384;
  u16*  wob  = wbb + 16384;   // 49152 u16

  k_prepack<<<dim3(448),  dim3(256), 0, stream>>>(Wq, Wk, Wv, Wb, Wo, wqb, wkb, wvb, wbb, wob);
  k_pass1  <<<dim3(512),  dim3(512), 0, stream>>>(t1, t2, t3, fs, wkb, wvb, pkv, pks);
  k_reduce <<<dim3(144),  dim3(256), 0, stream>>>(pkv, pks, kvb, ksf);
  k_pass2  <<<dim3(2048), dim3(512), 0, stream>>>(t1, t2, t3, fs, wqb, wbb, wob, kvb, ksf, outp);
}